// Round 2
// baseline (4965.620 us; speedup 1.0000x reference)
//
#include <hip/hip_runtime.h>
#include <hip/hip_bf16.h>
#include <stdint.h>

// Problem constants
#define TT 256
#define BB 64
#define DIN 512
#define RR 2048
#define DOUT 128
#define NTOT (RR*RR)                // 4194304
#define NKEEP 838860                // int(4194304 * (1.0 - 0.8)) in IEEE double
#define BETA 0.9f
#define VTH 1.0f

// ---------------- workspace layout ----------------
// drive : float [16384][2048]   @ 0            (134217728 B)
// mask  : u32   [256][64][64]   @ 134217728    (4 MB)  spike bitmask per (t,b)
// flags : u64   [256][64]       @ +4MB         (128 KB) 8 producer bytes per (t,b)
// hist  : u32   [256]
// state : u32   [8]   (0: prefix, 1: remaining, 2: thresh bits)
// cnts  : u32   [2]   (0: spike count, 1: active count)
// NOTE: w_rec is masked IN PLACE (harness restores pristine inputs every launch).

__global__ void k_init(uint32_t* __restrict__ p, int n) {
    int i = blockIdx.x * blockDim.x + threadIdx.x;
    int stride = gridDim.x * blockDim.x;
    for (; i < n; i += stride) p[i] = 0u;
}

// ---------------- radix select (4 passes x 8 bits, k-th largest) ----------------
__global__ void k_hist(const float* __restrict__ w_rec, uint32_t* __restrict__ hist,
                       const uint32_t* __restrict__ state, int p) {
    __shared__ uint32_t lh[256];
    lh[threadIdx.x] = 0u;
    __syncthreads();
    uint32_t prefix = (p > 0) ? state[0] : 0u;
    int sh = 24 - 8 * p;
    int i = blockIdx.x * 256 + threadIdx.x;
    int stride = gridDim.x * 256;
    for (; i < NTOT; i += stride) {
        uint32_t u = __float_as_uint(fabsf(w_rec[i]));
        bool ok = (p == 0) || ((u >> (sh + 8)) == prefix);
        if (ok) atomicAdd(&lh[(u >> sh) & 255u], 1u);
    }
    __syncthreads();
    uint32_t v = lh[threadIdx.x];
    if (v) atomicAdd(&hist[threadIdx.x], v);
}

__global__ void k_select(uint32_t* __restrict__ hist, uint32_t* __restrict__ state, int p) {
    __shared__ uint32_t lh[256];
    int tid = threadIdx.x;
    lh[tid] = hist[tid];
    hist[tid] = 0u;            // ready for next pass
    __syncthreads();
    if (tid == 0) {
        uint32_t remaining = (p == 0) ? (uint32_t)NKEEP : state[1];
        int bin = 255;
        for (; bin > 0; --bin) {
            uint32_t c = lh[bin];
            if (c >= remaining) break;
            remaining -= c;
        }
        uint32_t pref = (p == 0) ? 0u : state[0];
        pref = (pref << 8) | (uint32_t)bin;
        state[0] = pref;
        state[1] = remaining;
        if (p == 3) state[2] = pref;   // full 32-bit pattern of threshold value
    }
}

// ---------------- fused: count actives + mask w_rec in place ----------------
__global__ void k_maskcount(float* __restrict__ w, const uint32_t* __restrict__ state,
                            uint32_t* __restrict__ cnts) {
    uint32_t th = state[2];
    uint32_t c = 0;
    int i = blockIdx.x * blockDim.x + threadIdx.x;       // float4 index
    int stride = gridDim.x * blockDim.x;
    for (; i < NTOT / 4; i += stride) {
        float4 v = *(float4*)&w[i * 4];
        if ((__float_as_uint(v.x) & 0x7fffffffu) >= th) c++; else v.x = 0.0f;
        if ((__float_as_uint(v.y) & 0x7fffffffu) >= th) c++; else v.y = 0.0f;
        if ((__float_as_uint(v.z) & 0x7fffffffu) >= th) c++; else v.z = 0.0f;
        if ((__float_as_uint(v.w) & 0x7fffffffu) >= th) c++; else v.w = 0.0f;
        *(float4*)&w[i * 4] = v;
    }
    for (int off = 32; off > 0; off >>= 1) c += __shfl_down(c, off);
    if ((threadIdx.x & 63) == 0 && c) atomicAdd(&cnts[1], c);
}

// ---------------- drive GEMM: [16384,512] x [512,2048] + b_in ----------------
__global__ __launch_bounds__(256) void k_drive(const float* __restrict__ x,
                                               const float* __restrict__ w_in,
                                               const float* __restrict__ b_in,
                                               float* __restrict__ drive) {
    __shared__ float As[8][128];
    __shared__ float Bs[8][128];
    const int m0 = blockIdx.x * 128;
    const int n0 = blockIdx.y * 128;
    const int tid = threadIdx.x;
    const int tx = tid & 15, ty = tid >> 4;
    const int ar = tid >> 1;
    const int ak = (tid & 1) * 4;
    const int bk = tid >> 5;
    const int bc = (tid & 31) * 4;
    float acc[8][8];
    #pragma unroll
    for (int i = 0; i < 8; ++i)
        #pragma unroll
        for (int j = 0; j < 8; ++j) acc[i][j] = 0.0f;

    for (int k0 = 0; k0 < DIN; k0 += 8) {
        float4 av = *(const float4*)&x[(m0 + ar) * DIN + k0 + ak];
        float4 bv = *(const float4*)&w_in[(size_t)(k0 + bk) * RR + n0 + bc];
        __syncthreads();
        As[ak + 0][ar] = av.x; As[ak + 1][ar] = av.y;
        As[ak + 2][ar] = av.z; As[ak + 3][ar] = av.w;
        *(float4*)&Bs[bk][bc] = bv;
        __syncthreads();
        #pragma unroll
        for (int kk = 0; kk < 8; ++kk) {
            float a[8], b[8];
            *(float4*)&a[0] = *(const float4*)&As[kk][ty * 8];
            *(float4*)&a[4] = *(const float4*)&As[kk][ty * 8 + 4];
            *(float4*)&b[0] = *(const float4*)&Bs[kk][tx * 8];
            *(float4*)&b[4] = *(const float4*)&Bs[kk][tx * 8 + 4];
            #pragma unroll
            for (int i = 0; i < 8; ++i)
                #pragma unroll
                for (int j = 0; j < 8; ++j)
                    acc[i][j] = fmaf(a[i], b[j], acc[i][j]);
        }
    }
    float bb[8];
    #pragma unroll
    for (int j = 0; j < 8; ++j) bb[j] = b_in[n0 + tx * 8 + j];
    #pragma unroll
    for (int i = 0; i < 8; ++i) {
        size_t row = (size_t)(m0 + ty * 8 + i) * RR + n0 + tx * 8;
        float4 v0, v1;
        v0.x = acc[i][0] + bb[0]; v0.y = acc[i][1] + bb[1];
        v0.z = acc[i][2] + bb[2]; v0.w = acc[i][3] + bb[3];
        v1.x = acc[i][4] + bb[4]; v1.y = acc[i][5] + bb[5];
        v1.z = acc[i][6] + bb[6]; v1.w = acc[i][7] + bb[7];
        *(float4*)&drive[row] = v0;
        *(float4*)&drive[row + 4] = v1;
    }
}

// ---------------- recurrent scan: 512 blocks = 64 batches x 8 col-groups ----------------
// Block = (batch b, 256-col group cg); cg = blk&7 keeps a col-group on one XCD so its
// 2 MB w_rec slice stays L2-resident. lane = column (1 V per lane), 4 waves walk the
// shared spike list with 32-deep coalesced 256 B gathers.
// R1: (a) gather deepened 16->32 outstanding loads/wave (latency-bound theory:
//     8 waves/CU x 16 deep = 128 reqs/CU sustains only ~2.5-3 TB/s/XCD at loaded L2
//     latency, below the 4.3 TB/s/XCD L2 ceiling);
//     (b) drive prefetch moved AFTER the flag release store -- __syncthreads drains
//     vmcnt(0), so the old placement put an HBM-latency load on the flag-publish
//     critical chain every step.
// SYNC: relaxed-atomic polls ONLY (acquire would buffer_inv the L2 every iteration);
// mask words are relaxed atomics (cache-bypass => coherent); flag store is release.
// NUMERICS: per-(b,c) chain = drive-first + ascending-row adds + V=fma(BETA,V,acc) --
// bit-identical to all prior passing rounds.
__global__ __launch_bounds__(256) void k_scan(const float* __restrict__ w_rec,
                                              const float* __restrict__ drive,
                                              uint32_t* mask, unsigned long long* flags,
                                              uint32_t* cnts) {
    __shared__ __align__(16) int s_list[RR];   // byte offsets (row*8192), 8 KB
    __shared__ int s_n;
    __shared__ uint32_t s_red[4];

    const int tid = threadIdx.x;
    const int blk = blockIdx.x;       // 0..511
    const int cg = blk & 7;           // col-group -> XCD (blockIdx %8 round-robin)
    const int b = blk >> 3;           // batch 0..63
    const int col = (cg << 8) + tid;  // this thread's column
    const int w = tid >> 6;           // wave id 0..3
    const int lane = tid & 63;
    const char* Wp = (const char*)(w_rec + col);

    float V = 0.f;
    uint32_t scnt = 0;
    float dv = drive[(size_t)b * RR + col];   // t = 0

    for (int t = 0; t < TT; ++t) {
        float a = dv;                 // start from drive (bit-exact chain order)
        if (t > 0) {
            if (tid == 0) {
                const unsigned long long* fl = &flags[(size_t)(t - 1) * BB + b];
                while (__hip_atomic_load(fl, __ATOMIC_RELAXED, __HIP_MEMORY_SCOPE_AGENT)
                       != ~0ull)
                    __builtin_amdgcn_s_sleep(1);
            }
            __syncthreads();
            if (tid < 64) {   // wave 0: load batch mask, build ascending spike list
                uint32_t m = __hip_atomic_load(&mask[((size_t)(t - 1) * BB + b) * 64 + tid],
                                               __ATOMIC_RELAXED, __HIP_MEMORY_SCOPE_AGENT);
                int p = __popc(m);
                int off = p;
                #pragma unroll
                for (int d = 1; d < 64; d <<= 1) {
                    int o = __shfl_up(off, d);
                    if (tid >= d) off += o;
                }
                if (tid == 63) s_n = off;
                int e = off - p;
                int base = tid << 5;
                while (m) {
                    int bit = __builtin_ctz(m);
                    m &= m - 1;
                    s_list[e++] = (base + bit) << 13;   // byte offset = row * 8192
                }
            }
            __syncthreads();
            const int n = s_n;
            int i = 0;
            for (; i + 32 <= n; i += 32) {             // 32 outstanding loads / wave
                int4 o0 = *(const int4*)&s_list[i];        // LDS broadcast b128
                int4 o1 = *(const int4*)&s_list[i + 4];
                int4 o2 = *(const int4*)&s_list[i + 8];
                int4 o3 = *(const int4*)&s_list[i + 12];
                int4 o4 = *(const int4*)&s_list[i + 16];
                int4 o5 = *(const int4*)&s_list[i + 20];
                int4 o6 = *(const int4*)&s_list[i + 24];
                int4 o7 = *(const int4*)&s_list[i + 28];
                float v[32];
                v[0]  = *(const float*)(Wp + o0.x);
                v[1]  = *(const float*)(Wp + o0.y);
                v[2]  = *(const float*)(Wp + o0.z);
                v[3]  = *(const float*)(Wp + o0.w);
                v[4]  = *(const float*)(Wp + o1.x);
                v[5]  = *(const float*)(Wp + o1.y);
                v[6]  = *(const float*)(Wp + o1.z);
                v[7]  = *(const float*)(Wp + o1.w);
                v[8]  = *(const float*)(Wp + o2.x);
                v[9]  = *(const float*)(Wp + o2.y);
                v[10] = *(const float*)(Wp + o2.z);
                v[11] = *(const float*)(Wp + o2.w);
                v[12] = *(const float*)(Wp + o3.x);
                v[13] = *(const float*)(Wp + o3.y);
                v[14] = *(const float*)(Wp + o3.z);
                v[15] = *(const float*)(Wp + o3.w);
                v[16] = *(const float*)(Wp + o4.x);
                v[17] = *(const float*)(Wp + o4.y);
                v[18] = *(const float*)(Wp + o4.z);
                v[19] = *(const float*)(Wp + o4.w);
                v[20] = *(const float*)(Wp + o5.x);
                v[21] = *(const float*)(Wp + o5.y);
                v[22] = *(const float*)(Wp + o5.z);
                v[23] = *(const float*)(Wp + o5.w);
                v[24] = *(const float*)(Wp + o6.x);
                v[25] = *(const float*)(Wp + o6.y);
                v[26] = *(const float*)(Wp + o6.z);
                v[27] = *(const float*)(Wp + o6.w);
                v[28] = *(const float*)(Wp + o7.x);
                v[29] = *(const float*)(Wp + o7.y);
                v[30] = *(const float*)(Wp + o7.z);
                v[31] = *(const float*)(Wp + o7.w);
                #pragma unroll
                for (int j = 0; j < 32; ++j) a += v[j];    // ascending order
            }
            for (; i + 16 <= n; i += 16) {
                int4 o0 = *(const int4*)&s_list[i];
                int4 o1 = *(const int4*)&s_list[i + 4];
                int4 o2 = *(const int4*)&s_list[i + 8];
                int4 o3 = *(const int4*)&s_list[i + 12];
                float v[16];
                v[0]  = *(const float*)(Wp + o0.x);
                v[1]  = *(const float*)(Wp + o0.y);
                v[2]  = *(const float*)(Wp + o0.z);
                v[3]  = *(const float*)(Wp + o0.w);
                v[4]  = *(const float*)(Wp + o1.x);
                v[5]  = *(const float*)(Wp + o1.y);
                v[6]  = *(const float*)(Wp + o1.z);
                v[7]  = *(const float*)(Wp + o1.w);
                v[8]  = *(const float*)(Wp + o2.x);
                v[9]  = *(const float*)(Wp + o2.y);
                v[10] = *(const float*)(Wp + o2.z);
                v[11] = *(const float*)(Wp + o2.w);
                v[12] = *(const float*)(Wp + o3.x);
                v[13] = *(const float*)(Wp + o3.y);
                v[14] = *(const float*)(Wp + o3.z);
                v[15] = *(const float*)(Wp + o3.w);
                #pragma unroll
                for (int j = 0; j < 16; ++j) a += v[j];
            }
            for (; i + 4 <= n; i += 4) {
                int4 o = *(const int4*)&s_list[i];
                float v0 = *(const float*)(Wp + o.x);
                float v1 = *(const float*)(Wp + o.y);
                float v2 = *(const float*)(Wp + o.z);
                float v3 = *(const float*)(Wp + o.w);
                a += v0; a += v1; a += v2; a += v3;
            }
            for (; i < n; ++i) a += *(const float*)(Wp + s_list[i]);
        }

        V = BETA * V + a;             // fma(BETA, V, drive + ascending sum)
        bool sp = V > VTH;
        if (sp) V -= VTH;

        unsigned long long bal = __ballot(sp);   // 64 cols of this wave
        if (lane == 0) {
            // u64 mask word (cg*4 + w) covers neurons [cg*256 + w*64, +64)
            __hip_atomic_store(
                (unsigned long long*)&mask[((size_t)t * BB + b) * 64] + (cg * 4 + w),
                bal, __ATOMIC_RELAXED, __HIP_MEMORY_SCOPE_AGENT);
            scnt += (uint32_t)__popcll(bal);
        }
        __syncthreads();   // drains all 4 waves' mask stores (vmcnt(0) before barrier)
        if (tid == 0)      // release: publish flag byte cg for (t,b)
            __hip_atomic_store((uint8_t*)&flags[(size_t)t * BB + b] + cg, (uint8_t)0xFF,
                               __ATOMIC_RELEASE, __HIP_MEMORY_SCOPE_AGENT);
        __builtin_amdgcn_sched_barrier(0);   // keep prefetch BELOW the release store
        if (t + 1 < TT)    // prefetch next drive; latency hides under next poll+list
            dv = drive[((size_t)(t + 1) * BB + b) * RR + col];
    }

    if (lane == 0) s_red[w] = scnt;
    __syncthreads();
    if (tid == 0) {
        uint32_t s = s_red[0] + s_red[1] + s_red[2] + s_red[3];
        if (s) atomicAdd(&cnts[0], s);
    }
}

// ---------------- head: logits[t,b,:] = s @ w_head + b_head (sparse gather) ----------------
__global__ __launch_bounds__(128) void k_head(const uint32_t* __restrict__ mask,
                                              const float* __restrict__ w_head,
                                              const float* __restrict__ b_head,
                                              float* __restrict__ logits) {
    __shared__ __align__(16) int s_list[RR];   // byte offsets (row*512), 8 KB
    __shared__ int s_n;
    int tb = blockIdx.x;        // t*64 + b
    int tid = threadIdx.x;      // 0..127
    if (tid < 64) {             // wave 0: build ascending spike list (same as k_scan)
        uint32_t m = mask[tb * 64 + tid];
        int p = __popc(m);
        int off = p;
        #pragma unroll
        for (int d = 1; d < 64; d <<= 1) {
            int o = __shfl_up(off, d);
            if (tid >= d) off += o;
        }
        if (tid == 63) s_n = off;
        int e = off - p;
        int base = tid << 5;
        while (m) {
            int bit = __builtin_ctz(m);
            m &= m - 1;
            s_list[e++] = (base + bit) << 9;   // byte offset = row * DOUT * 4
        }
    }
    __syncthreads();
    const char* Wp = (const char*)(w_head + tid);
    float acc = b_head[tid];
    const int n = s_n;
    int i = 0;
    for (; i + 8 <= n; i += 8) {
        int4 o0 = *(const int4*)&s_list[i];
        int4 o1 = *(const int4*)&s_list[i + 4];
        float v[8];
        v[0] = *(const float*)(Wp + o0.x);
        v[1] = *(const float*)(Wp + o0.y);
        v[2] = *(const float*)(Wp + o0.z);
        v[3] = *(const float*)(Wp + o0.w);
        v[4] = *(const float*)(Wp + o1.x);
        v[5] = *(const float*)(Wp + o1.y);
        v[6] = *(const float*)(Wp + o1.z);
        v[7] = *(const float*)(Wp + o1.w);
        #pragma unroll
        for (int j = 0; j < 8; ++j) acc += v[j];   // ascending order
    }
    for (; i < n; ++i) acc += *(const float*)(Wp + s_list[i]);
    logits[(size_t)tb * DOUT + tid] = acc;
}

__global__ __launch_bounds__(128) void k_readout(const float* __restrict__ logits,
                                                 float* __restrict__ readout) {
    int b = blockIdx.x, cidx = threadIdx.x;
    float s = 0.0f;
    for (int t = 0; t < TT; ++t)
        s += logits[(size_t)t * (BB * DOUT) + b * DOUT + cidx];
    readout[b * DOUT + cidx] = s * (1.0f / (float)TT);
}

__global__ void k_scalars(const uint32_t* __restrict__ cnts, float* __restrict__ out) {
    if (threadIdx.x == 0 && blockIdx.x == 0) {
        out[BB * DOUT + TT * BB * DOUT]     = (float)cnts[0] / (float)(TT * BB * RR);
        out[BB * DOUT + TT * BB * DOUT + 1] = (float)cnts[1] / (float)NTOT;
    }
}

extern "C" void kernel_launch(void* const* d_in, const int* in_sizes, int n_in,
                              void* d_out, int out_size, void* d_ws, size_t ws_size,
                              hipStream_t stream) {
    const float* x      = (const float*)d_in[0];
    const float* w_in   = (const float*)d_in[1];
    const float* b_in   = (const float*)d_in[2];
    float*       w_rec  = (float*)d_in[3];        // masked in place (restored each launch)
    const float* w_head = (const float*)d_in[4];
    const float* b_head = (const float*)d_in[5];
    float* out = (float*)d_out;

    float*    drive = (float*)d_ws;
    uint32_t* mask  = (uint32_t*)((char*)d_ws + 134217728u);
    unsigned long long* flags = (unsigned long long*)(mask + (TT * BB * 64));
    uint32_t* hist  = (uint32_t*)(flags + TT * BB);
    uint32_t* state = hist + 256;
    uint32_t* cnts  = state + 8;

    // zero flags + hist + state + cnts (contiguous; mask fully overwritten before read)
    k_init<<<64, 256, 0, stream>>>((uint32_t*)flags, TT * BB * 2 + 256 + 8 + 2);

    for (int p = 0; p < 4; ++p) {
        k_hist<<<1024, 256, 0, stream>>>(w_rec, hist, state, p);
        k_select<<<1, 256, 0, stream>>>(hist, state, p);
    }
    k_maskcount<<<1024, 256, 0, stream>>>(w_rec, state, cnts);

    k_drive<<<dim3(128, 16), 256, 0, stream>>>(x, w_in, b_in, drive);

    k_scan<<<512, 256, 0, stream>>>(w_rec, drive, mask, flags, cnts);

    k_head<<<TT * BB, 128, 0, stream>>>(mask, w_head, b_head, out + BB * DOUT);
    k_readout<<<BB, 128, 0, stream>>>(out + BB * DOUT, out);
    k_scalars<<<1, 64, 0, stream>>>(cnts, out);
}

// Round 3
// 4323.005 us; speedup vs baseline: 1.1487x; 1.1487x over previous
//
#include <hip/hip_runtime.h>
#include <hip/hip_bf16.h>
#include <stdint.h>

// Problem constants
#define TT 256
#define BB 64
#define DIN 512
#define RR 2048
#define DOUT 128
#define NTOT (RR*RR)                // 4194304
#define NKEEP 838860                // int(4194304 * (1.0 - 0.8)) in IEEE double
#define BETA 0.9f
#define VTH 1.0f

// ---------------- workspace layout ----------------
// drive : float [16384][2048]   @ 0            (134217728 B)
// mask  : u32   [256][64][64]   @ 134217728    (4 MB)  spike bitmask per (t,b)
// flags : u64   [256][64][16]   @ +4MB         (2 MB)  one 128B LINE per (t,b):
//         only u64[0] is used (8 producer bytes); padding kills line contention
//         (was 16 (t,b) per line -> 128 pollers + 8 writers per line per step).
// hist  : u32   [256]
// state : u32   [8]   (0: prefix, 1: remaining, 2: thresh bits)
// cnts  : u32   [2]   (0: spike count, 1: active count)
// NOTE: w_rec is masked IN PLACE (harness restores pristine inputs every launch).

#define FLAG_STRIDE 16   // u64s per (t,b) flag slot = 128 B line

__global__ void k_init(uint32_t* __restrict__ p, int n) {
    int i = blockIdx.x * blockDim.x + threadIdx.x;
    int stride = gridDim.x * blockDim.x;
    for (; i < n; i += stride) p[i] = 0u;
}

// ---------------- radix select (4 passes x 8 bits, k-th largest) ----------------
__global__ void k_hist(const float* __restrict__ w_rec, uint32_t* __restrict__ hist,
                       const uint32_t* __restrict__ state, int p) {
    __shared__ uint32_t lh[256];
    lh[threadIdx.x] = 0u;
    __syncthreads();
    uint32_t prefix = (p > 0) ? state[0] : 0u;
    int sh = 24 - 8 * p;
    int i = blockIdx.x * 256 + threadIdx.x;
    int stride = gridDim.x * 256;
    for (; i < NTOT; i += stride) {
        uint32_t u = __float_as_uint(fabsf(w_rec[i]));
        bool ok = (p == 0) || ((u >> (sh + 8)) == prefix);
        if (ok) atomicAdd(&lh[(u >> sh) & 255u], 1u);
    }
    __syncthreads();
    uint32_t v = lh[threadIdx.x];
    if (v) atomicAdd(&hist[threadIdx.x], v);
}

__global__ void k_select(uint32_t* __restrict__ hist, uint32_t* __restrict__ state, int p) {
    __shared__ uint32_t lh[256];
    int tid = threadIdx.x;
    lh[tid] = hist[tid];
    hist[tid] = 0u;            // ready for next pass
    __syncthreads();
    if (tid == 0) {
        uint32_t remaining = (p == 0) ? (uint32_t)NKEEP : state[1];
        int bin = 255;
        for (; bin > 0; --bin) {
            uint32_t c = lh[bin];
            if (c >= remaining) break;
            remaining -= c;
        }
        uint32_t pref = (p == 0) ? 0u : state[0];
        pref = (pref << 8) | (uint32_t)bin;
        state[0] = pref;
        state[1] = remaining;
        if (p == 3) state[2] = pref;   // full 32-bit pattern of threshold value
    }
}

// ---------------- fused: count actives + mask w_rec in place ----------------
__global__ void k_maskcount(float* __restrict__ w, const uint32_t* __restrict__ state,
                            uint32_t* __restrict__ cnts) {
    uint32_t th = state[2];
    uint32_t c = 0;
    int i = blockIdx.x * blockDim.x + threadIdx.x;       // float4 index
    int stride = gridDim.x * blockDim.x;
    for (; i < NTOT / 4; i += stride) {
        float4 v = *(float4*)&w[i * 4];
        if ((__float_as_uint(v.x) & 0x7fffffffu) >= th) c++; else v.x = 0.0f;
        if ((__float_as_uint(v.y) & 0x7fffffffu) >= th) c++; else v.y = 0.0f;
        if ((__float_as_uint(v.z) & 0x7fffffffu) >= th) c++; else v.z = 0.0f;
        if ((__float_as_uint(v.w) & 0x7fffffffu) >= th) c++; else v.w = 0.0f;
        *(float4*)&w[i * 4] = v;
    }
    for (int off = 32; off > 0; off >>= 1) c += __shfl_down(c, off);
    if ((threadIdx.x & 63) == 0 && c) atomicAdd(&cnts[1], c);
}

// ---------------- drive GEMM: [16384,512] x [512,2048] + b_in ----------------
__global__ __launch_bounds__(256) void k_drive(const float* __restrict__ x,
                                               const float* __restrict__ w_in,
                                               const float* __restrict__ b_in,
                                               float* __restrict__ drive) {
    __shared__ float As[8][128];
    __shared__ float Bs[8][128];
    const int m0 = blockIdx.x * 128;
    const int n0 = blockIdx.y * 128;
    const int tid = threadIdx.x;
    const int tx = tid & 15, ty = tid >> 4;
    const int ar = tid >> 1;
    const int ak = (tid & 1) * 4;
    const int bk = tid >> 5;
    const int bc = (tid & 31) * 4;
    float acc[8][8];
    #pragma unroll
    for (int i = 0; i < 8; ++i)
        #pragma unroll
        for (int j = 0; j < 8; ++j) acc[i][j] = 0.0f;

    for (int k0 = 0; k0 < DIN; k0 += 8) {
        float4 av = *(const float4*)&x[(m0 + ar) * DIN + k0 + ak];
        float4 bv = *(const float4*)&w_in[(size_t)(k0 + bk) * RR + n0 + bc];
        __syncthreads();
        As[ak + 0][ar] = av.x; As[ak + 1][ar] = av.y;
        As[ak + 2][ar] = av.z; As[ak + 3][ar] = av.w;
        *(float4*)&Bs[bk][bc] = bv;
        __syncthreads();
        #pragma unroll
        for (int kk = 0; kk < 8; ++kk) {
            float a[8], b[8];
            *(float4*)&a[0] = *(const float4*)&As[kk][ty * 8];
            *(float4*)&a[4] = *(const float4*)&As[kk][ty * 8 + 4];
            *(float4*)&b[0] = *(const float4*)&Bs[kk][tx * 8];
            *(float4*)&b[4] = *(const float4*)&Bs[kk][tx * 8 + 4];
            #pragma unroll
            for (int i = 0; i < 8; ++i)
                #pragma unroll
                for (int j = 0; j < 8; ++j)
                    acc[i][j] = fmaf(a[i], b[j], acc[i][j]);
        }
    }
    float bb[8];
    #pragma unroll
    for (int j = 0; j < 8; ++j) bb[j] = b_in[n0 + tx * 8 + j];
    #pragma unroll
    for (int i = 0; i < 8; ++i) {
        size_t row = (size_t)(m0 + ty * 8 + i) * RR + n0 + tx * 8;
        float4 v0, v1;
        v0.x = acc[i][0] + bb[0]; v0.y = acc[i][1] + bb[1];
        v0.z = acc[i][2] + bb[2]; v0.w = acc[i][3] + bb[3];
        v1.x = acc[i][4] + bb[4]; v1.y = acc[i][5] + bb[5];
        v1.z = acc[i][6] + bb[6]; v1.w = acc[i][7] + bb[7];
        *(float4*)&drive[row] = v0;
        *(float4*)&drive[row + 4] = v1;
    }
}

// ---------------- recurrent scan: 512 blocks = 64 batches x 8 col-groups ----------------
// Block = (batch b, 256-col group cg); cg = blk&7 keeps a col-group on one XCD so its
// 2 MB w_rec slice stays L2-resident. lane = column (1 V per lane), 4 waves walk the
// shared spike list with 32-deep coalesced 256 B gathers.
// R2: (a) __launch_bounds__(256,2): occupancy is block-limited at 2 blocks/CU
//     (= 2 waves/EU), so raise the reg cap -- R1's 32-deep gather never allocated
//     (VGPR_Count stayed 32 => compiler re-serialized to ~8 in flight);
//     (b) flags padded to one 128B line per (t,b) -- was 16 slots/line => 128
//     pollers + 8 atomic writers hammering each line every step.
// SYNC: relaxed-atomic polls ONLY (acquire would buffer_inv the L2 every iteration);
// mask words are relaxed atomics (cache-bypass => coherent); flag store is release.
// NUMERICS: per-(b,c) chain = drive-first + ascending-row adds + V=fma(BETA,V,acc) --
// bit-identical to all prior passing rounds.
__global__ __launch_bounds__(256, 2) void k_scan(const float* __restrict__ w_rec,
                                                 const float* __restrict__ drive,
                                                 uint32_t* mask, unsigned long long* flags,
                                                 uint32_t* cnts) {
    __shared__ __align__(16) int s_list[RR];   // byte offsets (row*8192), 8 KB
    __shared__ int s_n;
    __shared__ uint32_t s_red[4];

    const int tid = threadIdx.x;
    const int blk = blockIdx.x;       // 0..511
    const int cg = blk & 7;           // col-group -> XCD (blockIdx %8 round-robin)
    const int b = blk >> 3;           // batch 0..63
    const int col = (cg << 8) + tid;  // this thread's column
    const int w = tid >> 6;           // wave id 0..3
    const int lane = tid & 63;
    const char* Wp = (const char*)(w_rec + col);

    float V = 0.f;
    uint32_t scnt = 0;
    float dv = drive[(size_t)b * RR + col];   // t = 0

    for (int t = 0; t < TT; ++t) {
        float a = dv;                 // start from drive (bit-exact chain order)
        if (t > 0) {
            if (tid == 0) {
                const unsigned long long* fl =
                    &flags[(size_t)((t - 1) * BB + b) * FLAG_STRIDE];
                while (__hip_atomic_load(fl, __ATOMIC_RELAXED, __HIP_MEMORY_SCOPE_AGENT)
                       != ~0ull)
                    __builtin_amdgcn_s_sleep(1);
            }
            __syncthreads();
            if (tid < 64) {   // wave 0: load batch mask, build ascending spike list
                uint32_t m = __hip_atomic_load(&mask[((size_t)(t - 1) * BB + b) * 64 + tid],
                                               __ATOMIC_RELAXED, __HIP_MEMORY_SCOPE_AGENT);
                int p = __popc(m);
                int off = p;
                #pragma unroll
                for (int d = 1; d < 64; d <<= 1) {
                    int o = __shfl_up(off, d);
                    if (tid >= d) off += o;
                }
                if (tid == 63) s_n = off;
                int e = off - p;
                int base = tid << 5;
                while (m) {
                    int bit = __builtin_ctz(m);
                    m &= m - 1;
                    s_list[e++] = (base + bit) << 13;   // byte offset = row * 8192
                }
            }
            __syncthreads();
            const int n = s_n;
            int i = 0;
            for (; i + 32 <= n; i += 32) {             // 32 outstanding loads / wave
                int4 o0 = *(const int4*)&s_list[i];        // LDS broadcast b128
                int4 o1 = *(const int4*)&s_list[i + 4];
                int4 o2 = *(const int4*)&s_list[i + 8];
                int4 o3 = *(const int4*)&s_list[i + 12];
                int4 o4 = *(const int4*)&s_list[i + 16];
                int4 o5 = *(const int4*)&s_list[i + 20];
                int4 o6 = *(const int4*)&s_list[i + 24];
                int4 o7 = *(const int4*)&s_list[i + 28];
                float v[32];
                v[0]  = *(const float*)(Wp + o0.x);
                v[1]  = *(const float*)(Wp + o0.y);
                v[2]  = *(const float*)(Wp + o0.z);
                v[3]  = *(const float*)(Wp + o0.w);
                v[4]  = *(const float*)(Wp + o1.x);
                v[5]  = *(const float*)(Wp + o1.y);
                v[6]  = *(const float*)(Wp + o1.z);
                v[7]  = *(const float*)(Wp + o1.w);
                v[8]  = *(const float*)(Wp + o2.x);
                v[9]  = *(const float*)(Wp + o2.y);
                v[10] = *(const float*)(Wp + o2.z);
                v[11] = *(const float*)(Wp + o2.w);
                v[12] = *(const float*)(Wp + o3.x);
                v[13] = *(const float*)(Wp + o3.y);
                v[14] = *(const float*)(Wp + o3.z);
                v[15] = *(const float*)(Wp + o3.w);
                v[16] = *(const float*)(Wp + o4.x);
                v[17] = *(const float*)(Wp + o4.y);
                v[18] = *(const float*)(Wp + o4.z);
                v[19] = *(const float*)(Wp + o4.w);
                v[20] = *(const float*)(Wp + o5.x);
                v[21] = *(const float*)(Wp + o5.y);
                v[22] = *(const float*)(Wp + o5.z);
                v[23] = *(const float*)(Wp + o5.w);
                v[24] = *(const float*)(Wp + o6.x);
                v[25] = *(const float*)(Wp + o6.y);
                v[26] = *(const float*)(Wp + o6.z);
                v[27] = *(const float*)(Wp + o6.w);
                v[28] = *(const float*)(Wp + o7.x);
                v[29] = *(const float*)(Wp + o7.y);
                v[30] = *(const float*)(Wp + o7.z);
                v[31] = *(const float*)(Wp + o7.w);
                #pragma unroll
                for (int j = 0; j < 32; ++j) a += v[j];    // ascending order
            }
            for (; i + 16 <= n; i += 16) {
                int4 o0 = *(const int4*)&s_list[i];
                int4 o1 = *(const int4*)&s_list[i + 4];
                int4 o2 = *(const int4*)&s_list[i + 8];
                int4 o3 = *(const int4*)&s_list[i + 12];
                float v[16];
                v[0]  = *(const float*)(Wp + o0.x);
                v[1]  = *(const float*)(Wp + o0.y);
                v[2]  = *(const float*)(Wp + o0.z);
                v[3]  = *(const float*)(Wp + o0.w);
                v[4]  = *(const float*)(Wp + o1.x);
                v[5]  = *(const float*)(Wp + o1.y);
                v[6]  = *(const float*)(Wp + o1.z);
                v[7]  = *(const float*)(Wp + o1.w);
                v[8]  = *(const float*)(Wp + o2.x);
                v[9]  = *(const float*)(Wp + o2.y);
                v[10] = *(const float*)(Wp + o2.z);
                v[11] = *(const float*)(Wp + o2.w);
                v[12] = *(const float*)(Wp + o3.x);
                v[13] = *(const float*)(Wp + o3.y);
                v[14] = *(const float*)(Wp + o3.z);
                v[15] = *(const float*)(Wp + o3.w);
                #pragma unroll
                for (int j = 0; j < 16; ++j) a += v[j];
            }
            for (; i + 4 <= n; i += 4) {
                int4 o = *(const int4*)&s_list[i];
                float v0 = *(const float*)(Wp + o.x);
                float v1 = *(const float*)(Wp + o.y);
                float v2 = *(const float*)(Wp + o.z);
                float v3 = *(const float*)(Wp + o.w);
                a += v0; a += v1; a += v2; a += v3;
            }
            for (; i < n; ++i) a += *(const float*)(Wp + s_list[i]);
        }

        V = BETA * V + a;             // fma(BETA, V, drive + ascending sum)
        bool sp = V > VTH;
        if (sp) V -= VTH;

        unsigned long long bal = __ballot(sp);   // 64 cols of this wave
        if (lane == 0) {
            // u64 mask word (cg*4 + w) covers neurons [cg*256 + w*64, +64)
            __hip_atomic_store(
                (unsigned long long*)&mask[((size_t)t * BB + b) * 64] + (cg * 4 + w),
                bal, __ATOMIC_RELAXED, __HIP_MEMORY_SCOPE_AGENT);
            scnt += (uint32_t)__popcll(bal);
        }
        __syncthreads();   // drains all 4 waves' mask stores (vmcnt(0) before barrier)
        if (tid == 0)      // release: publish flag byte cg for (t,b)
            __hip_atomic_store(
                (uint8_t*)&flags[(size_t)(t * BB + b) * FLAG_STRIDE] + cg, (uint8_t)0xFF,
                __ATOMIC_RELEASE, __HIP_MEMORY_SCOPE_AGENT);
        __builtin_amdgcn_sched_barrier(0);   // keep prefetch BELOW the release store
        if (t + 1 < TT)    // prefetch next drive; latency hides under next poll+list
            dv = drive[((size_t)(t + 1) * BB + b) * RR + col];
    }

    if (lane == 0) s_red[w] = scnt;
    __syncthreads();
    if (tid == 0) {
        uint32_t s = s_red[0] + s_red[1] + s_red[2] + s_red[3];
        if (s) atomicAdd(&cnts[0], s);
    }
}

// ---------------- head: logits[t,b,:] = s @ w_head + b_head (sparse gather) ----------------
__global__ __launch_bounds__(128) void k_head(const uint32_t* __restrict__ mask,
                                              const float* __restrict__ w_head,
                                              const float* __restrict__ b_head,
                                              float* __restrict__ logits) {
    __shared__ __align__(16) int s_list[RR];   // byte offsets (row*512), 8 KB
    __shared__ int s_n;
    int tb = blockIdx.x;        // t*64 + b
    int tid = threadIdx.x;      // 0..127
    if (tid < 64) {             // wave 0: build ascending spike list (same as k_scan)
        uint32_t m = mask[tb * 64 + tid];
        int p = __popc(m);
        int off = p;
        #pragma unroll
        for (int d = 1; d < 64; d <<= 1) {
            int o = __shfl_up(off, d);
            if (tid >= d) off += o;
        }
        if (tid == 63) s_n = off;
        int e = off - p;
        int base = tid << 5;
        while (m) {
            int bit = __builtin_ctz(m);
            m &= m - 1;
            s_list[e++] = (base + bit) << 9;   // byte offset = row * DOUT * 4
        }
    }
    __syncthreads();
    const char* Wp = (const char*)(w_head + tid);
    float acc = b_head[tid];
    const int n = s_n;
    int i = 0;
    for (; i + 8 <= n; i += 8) {
        int4 o0 = *(const int4*)&s_list[i];
        int4 o1 = *(const int4*)&s_list[i + 4];
        float v[8];
        v[0] = *(const float*)(Wp + o0.x);
        v[1] = *(const float*)(Wp + o0.y);
        v[2] = *(const float*)(Wp + o0.z);
        v[3] = *(const float*)(Wp + o0.w);
        v[4] = *(const float*)(Wp + o1.x);
        v[5] = *(const float*)(Wp + o1.y);
        v[6] = *(const float*)(Wp + o1.z);
        v[7] = *(const float*)(Wp + o1.w);
        #pragma unroll
        for (int j = 0; j < 8; ++j) acc += v[j];   // ascending order
    }
    for (; i < n; ++i) acc += *(const float*)(Wp + s_list[i]);
    logits[(size_t)tb * DOUT + tid] = acc;
}

__global__ __launch_bounds__(128) void k_readout(const float* __restrict__ logits,
                                                 float* __restrict__ readout) {
    int b = blockIdx.x, cidx = threadIdx.x;
    float s = 0.0f;
    for (int t = 0; t < TT; ++t)
        s += logits[(size_t)t * (BB * DOUT) + b * DOUT + cidx];
    readout[b * DOUT + cidx] = s * (1.0f / (float)TT);
}

__global__ void k_scalars(const uint32_t* __restrict__ cnts, float* __restrict__ out) {
    if (threadIdx.x == 0 && blockIdx.x == 0) {
        out[BB * DOUT + TT * BB * DOUT]     = (float)cnts[0] / (float)(TT * BB * RR);
        out[BB * DOUT + TT * BB * DOUT + 1] = (float)cnts[1] / (float)NTOT;
    }
}

extern "C" void kernel_launch(void* const* d_in, const int* in_sizes, int n_in,
                              void* d_out, int out_size, void* d_ws, size_t ws_size,
                              hipStream_t stream) {
    const float* x      = (const float*)d_in[0];
    const float* w_in   = (const float*)d_in[1];
    const float* b_in   = (const float*)d_in[2];
    float*       w_rec  = (float*)d_in[3];        // masked in place (restored each launch)
    const float* w_head = (const float*)d_in[4];
    const float* b_head = (const float*)d_in[5];
    float* out = (float*)d_out;

    float*    drive = (float*)d_ws;
    uint32_t* mask  = (uint32_t*)((char*)d_ws + 134217728u);
    unsigned long long* flags = (unsigned long long*)(mask + (TT * BB * 64));
    uint32_t* hist  = (uint32_t*)(flags + (size_t)TT * BB * FLAG_STRIDE);
    uint32_t* state = hist + 256;
    uint32_t* cnts  = state + 8;

    // zero flags + hist + state + cnts (contiguous; mask fully overwritten before read)
    k_init<<<256, 256, 0, stream>>>((uint32_t*)flags,
                                    TT * BB * FLAG_STRIDE * 2 + 256 + 8 + 2);

    for (int p = 0; p < 4; ++p) {
        k_hist<<<1024, 256, 0, stream>>>(w_rec, hist, state, p);
        k_select<<<1, 256, 0, stream>>>(hist, state, p);
    }
    k_maskcount<<<1024, 256, 0, stream>>>(w_rec, state, cnts);

    k_drive<<<dim3(128, 16), 256, 0, stream>>>(x, w_in, b_in, drive);

    k_scan<<<512, 256, 0, stream>>>(w_rec, drive, mask, flags, cnts);

    k_head<<<TT * BB, 128, 0, stream>>>(mask, w_head, b_head, out + BB * DOUT);
    k_readout<<<BB, 128, 0, stream>>>(out + BB * DOUT, out);
    k_scalars<<<1, 64, 0, stream>>>(cnts, out);
}

// Round 4
// 4283.220 us; speedup vs baseline: 1.1593x; 1.0093x over previous
//
#include <hip/hip_runtime.h>
#include <hip/hip_bf16.h>
#include <stdint.h>

// Problem constants
#define TT 256
#define BB 64
#define DIN 512
#define RR 2048
#define DOUT 128
#define NTOT (RR*RR)                // 4194304
#define NKEEP 838860                // int(4194304 * (1.0 - 0.8)) in IEEE double
#define BETA 0.9f
#define VTH 1.0f

// ---------------- workspace layout ----------------
// drive : float [16384][2048]   @ 0            (134217728 B)
// mask  : u32   [256][64][64]   @ 134217728    (4 MB)  spike bitmask per (t,b)
// flags : u64   [256][64][16]   @ +4MB         (2 MB)  one 128B LINE per (t,b)
// hist  : u32   [256]
// state : u32   [8]   (0: prefix, 1: remaining, 2: thresh bits)
// cnts  : u32   [2]   (0: spike count, 1: active count)
// NOTE: w_rec is masked IN PLACE (harness restores pristine inputs every launch).

#define FLAG_STRIDE 16   // u64s per (t,b) flag slot = 128 B line

__global__ void k_init(uint32_t* __restrict__ p, int n) {
    int i = blockIdx.x * blockDim.x + threadIdx.x;
    int stride = gridDim.x * blockDim.x;
    for (; i < n; i += stride) p[i] = 0u;
}

// ---------------- radix select (4 passes x 8 bits, k-th largest) ----------------
__global__ void k_hist(const float* __restrict__ w_rec, uint32_t* __restrict__ hist,
                       const uint32_t* __restrict__ state, int p) {
    __shared__ uint32_t lh[256];
    lh[threadIdx.x] = 0u;
    __syncthreads();
    uint32_t prefix = (p > 0) ? state[0] : 0u;
    int sh = 24 - 8 * p;
    int i = blockIdx.x * 256 + threadIdx.x;
    int stride = gridDim.x * 256;
    for (; i < NTOT; i += stride) {
        uint32_t u = __float_as_uint(fabsf(w_rec[i]));
        bool ok = (p == 0) || ((u >> (sh + 8)) == prefix);
        if (ok) atomicAdd(&lh[(u >> sh) & 255u], 1u);
    }
    __syncthreads();
    uint32_t v = lh[threadIdx.x];
    if (v) atomicAdd(&hist[threadIdx.x], v);
}

__global__ void k_select(uint32_t* __restrict__ hist, uint32_t* __restrict__ state, int p) {
    __shared__ uint32_t lh[256];
    int tid = threadIdx.x;
    lh[tid] = hist[tid];
    hist[tid] = 0u;            // ready for next pass
    __syncthreads();
    if (tid == 0) {
        uint32_t remaining = (p == 0) ? (uint32_t)NKEEP : state[1];
        int bin = 255;
        for (; bin > 0; --bin) {
            uint32_t c = lh[bin];
            if (c >= remaining) break;
            remaining -= c;
        }
        uint32_t pref = (p == 0) ? 0u : state[0];
        pref = (pref << 8) | (uint32_t)bin;
        state[0] = pref;
        state[1] = remaining;
        if (p == 3) state[2] = pref;   // full 32-bit pattern of threshold value
    }
}

// ---------------- fused: count actives + mask w_rec in place ----------------
__global__ void k_maskcount(float* __restrict__ w, const uint32_t* __restrict__ state,
                            uint32_t* __restrict__ cnts) {
    uint32_t th = state[2];
    uint32_t c = 0;
    int i = blockIdx.x * blockDim.x + threadIdx.x;       // float4 index
    int stride = gridDim.x * blockDim.x;
    for (; i < NTOT / 4; i += stride) {
        float4 v = *(float4*)&w[i * 4];
        if ((__float_as_uint(v.x) & 0x7fffffffu) >= th) c++; else v.x = 0.0f;
        if ((__float_as_uint(v.y) & 0x7fffffffu) >= th) c++; else v.y = 0.0f;
        if ((__float_as_uint(v.z) & 0x7fffffffu) >= th) c++; else v.z = 0.0f;
        if ((__float_as_uint(v.w) & 0x7fffffffu) >= th) c++; else v.w = 0.0f;
        *(float4*)&w[i * 4] = v;
    }
    for (int off = 32; off > 0; off >>= 1) c += __shfl_down(c, off);
    if ((threadIdx.x & 63) == 0 && c) atomicAdd(&cnts[1], c);
}

// ---------------- drive GEMM: [16384,512] x [512,2048] + b_in ----------------
__global__ __launch_bounds__(256) void k_drive(const float* __restrict__ x,
                                               const float* __restrict__ w_in,
                                               const float* __restrict__ b_in,
                                               float* __restrict__ drive) {
    __shared__ float As[8][128];
    __shared__ float Bs[8][128];
    const int m0 = blockIdx.x * 128;
    const int n0 = blockIdx.y * 128;
    const int tid = threadIdx.x;
    const int tx = tid & 15, ty = tid >> 4;
    const int ar = tid >> 1;
    const int ak = (tid & 1) * 4;
    const int bk = tid >> 5;
    const int bc = (tid & 31) * 4;
    float acc[8][8];
    #pragma unroll
    for (int i = 0; i < 8; ++i)
        #pragma unroll
        for (int j = 0; j < 8; ++j) acc[i][j] = 0.0f;

    for (int k0 = 0; k0 < DIN; k0 += 8) {
        float4 av = *(const float4*)&x[(m0 + ar) * DIN + k0 + ak];
        float4 bv = *(const float4*)&w_in[(size_t)(k0 + bk) * RR + n0 + bc];
        __syncthreads();
        As[ak + 0][ar] = av.x; As[ak + 1][ar] = av.y;
        As[ak + 2][ar] = av.z; As[ak + 3][ar] = av.w;
        *(float4*)&Bs[bk][bc] = bv;
        __syncthreads();
        #pragma unroll
        for (int kk = 0; kk < 8; ++kk) {
            float a[8], b[8];
            *(float4*)&a[0] = *(const float4*)&As[kk][ty * 8];
            *(float4*)&a[4] = *(const float4*)&As[kk][ty * 8 + 4];
            *(float4*)&b[0] = *(const float4*)&Bs[kk][tx * 8];
            *(float4*)&b[4] = *(const float4*)&Bs[kk][tx * 8 + 4];
            #pragma unroll
            for (int i = 0; i < 8; ++i)
                #pragma unroll
                for (int j = 0; j < 8; ++j)
                    acc[i][j] = fmaf(a[i], b[j], acc[i][j]);
        }
    }
    float bb[8];
    #pragma unroll
    for (int j = 0; j < 8; ++j) bb[j] = b_in[n0 + tx * 8 + j];
    #pragma unroll
    for (int i = 0; i < 8; ++i) {
        size_t row = (size_t)(m0 + ty * 8 + i) * RR + n0 + tx * 8;
        float4 v0, v1;
        v0.x = acc[i][0] + bb[0]; v0.y = acc[i][1] + bb[1];
        v0.z = acc[i][2] + bb[2]; v0.w = acc[i][3] + bb[3];
        v1.x = acc[i][4] + bb[4]; v1.y = acc[i][5] + bb[5];
        v1.z = acc[i][6] + bb[6]; v1.w = acc[i][7] + bb[7];
        *(float4*)&drive[row] = v0;
        *(float4*)&drive[row + 4] = v1;
    }
}

// ---------------- recurrent scan: 512 blocks = 64 batches x 8 col-groups ----------------
// Block = (batch b, 256-col group cg); cg = blk&7 keeps a col-group on one XCD so its
// 2 MB w_rec slice stays L2-resident. lane = column (1 V per lane), 4 waves walk the
// shared spike list.
// R3: FORCED 64-deep gather. R1/R2's deep batch never allocated (VGPR stayed 32;
//     scheduler re-serialized to ~8 in flight). Now: issue 64 loads, then
//     sched_barrier(0), then the 64 ascending adds -- all 64 values are live at the
//     barrier, so the allocator MUST materialize the pipeline (expect VGPR ~150-220).
//     Next iteration's loads may legally hoist above the add chain => continuous issue.
// SYNC: relaxed-atomic polls ONLY; flags padded 1 line/(t,b); flag store is release.
// NUMERICS: per-(b,c) chain = drive-first + ascending-row adds + V=fma(BETA,V,acc) --
// bit-identical to all prior passing rounds.
__global__ __launch_bounds__(256, 2) void k_scan(const float* __restrict__ w_rec,
                                                 const float* __restrict__ drive,
                                                 uint32_t* mask, unsigned long long* flags,
                                                 uint32_t* cnts) {
    __shared__ __align__(16) int s_list[RR];   // byte offsets (row*8192), 8 KB
    __shared__ int s_n;
    __shared__ uint32_t s_red[4];

    const int tid = threadIdx.x;
    const int blk = blockIdx.x;       // 0..511
    const int cg = blk & 7;           // col-group -> XCD (blockIdx %8 round-robin)
    const int b = blk >> 3;           // batch 0..63
    const int col = (cg << 8) + tid;  // this thread's column
    const int w = tid >> 6;           // wave id 0..3
    const int lane = tid & 63;
    const char* Wp = (const char*)(w_rec + col);

    float V = 0.f;
    uint32_t scnt = 0;
    float dv = drive[(size_t)b * RR + col];   // t = 0

    for (int t = 0; t < TT; ++t) {
        float a = dv;                 // start from drive (bit-exact chain order)
        if (t > 0) {
            if (tid == 0) {
                const unsigned long long* fl =
                    &flags[(size_t)((t - 1) * BB + b) * FLAG_STRIDE];
                while (__hip_atomic_load(fl, __ATOMIC_RELAXED, __HIP_MEMORY_SCOPE_AGENT)
                       != ~0ull)
                    __builtin_amdgcn_s_sleep(1);
            }
            __syncthreads();
            if (tid < 64) {   // wave 0: load batch mask, build ascending spike list
                uint32_t m = __hip_atomic_load(&mask[((size_t)(t - 1) * BB + b) * 64 + tid],
                                               __ATOMIC_RELAXED, __HIP_MEMORY_SCOPE_AGENT);
                int p = __popc(m);
                int off = p;
                #pragma unroll
                for (int d = 1; d < 64; d <<= 1) {
                    int o = __shfl_up(off, d);
                    if (tid >= d) off += o;
                }
                if (tid == 63) s_n = off;
                int e = off - p;
                int base = tid << 5;
                while (m) {
                    int bit = __builtin_ctz(m);
                    m &= m - 1;
                    s_list[e++] = (base + bit) << 13;   // byte offset = row * 8192
                }
            }
            __syncthreads();
            const int n = s_n;
            int i = 0;
            for (; i + 64 <= n; i += 64) {   // 64 loads issued, THEN 64 adds (pinned)
                float v[64];
                #pragma unroll
                for (int u = 0; u < 64; u += 4) {
                    int4 o = *(const int4*)&s_list[i + u];   // LDS broadcast b128
                    v[u + 0] = *(const float*)(Wp + o.x);
                    v[u + 1] = *(const float*)(Wp + o.y);
                    v[u + 2] = *(const float*)(Wp + o.z);
                    v[u + 3] = *(const float*)(Wp + o.w);
                }
                __builtin_amdgcn_sched_barrier(0);   // all 64 loads precede all adds
                #pragma unroll
                for (int j = 0; j < 64; ++j) a += v[j];    // ascending order
            }
            for (; i + 16 <= n; i += 16) {
                float v[16];
                #pragma unroll
                for (int u = 0; u < 16; u += 4) {
                    int4 o = *(const int4*)&s_list[i + u];
                    v[u + 0] = *(const float*)(Wp + o.x);
                    v[u + 1] = *(const float*)(Wp + o.y);
                    v[u + 2] = *(const float*)(Wp + o.z);
                    v[u + 3] = *(const float*)(Wp + o.w);
                }
                __builtin_amdgcn_sched_barrier(0);
                #pragma unroll
                for (int j = 0; j < 16; ++j) a += v[j];
            }
            for (; i + 4 <= n; i += 4) {
                int4 o = *(const int4*)&s_list[i];
                float v0 = *(const float*)(Wp + o.x);
                float v1 = *(const float*)(Wp + o.y);
                float v2 = *(const float*)(Wp + o.z);
                float v3 = *(const float*)(Wp + o.w);
                a += v0; a += v1; a += v2; a += v3;
            }
            for (; i < n; ++i) a += *(const float*)(Wp + s_list[i]);
        }

        V = BETA * V + a;             // fma(BETA, V, drive + ascending sum)
        bool sp = V > VTH;
        if (sp) V -= VTH;

        unsigned long long bal = __ballot(sp);   // 64 cols of this wave
        if (lane == 0) {
            // u64 mask word (cg*4 + w) covers neurons [cg*256 + w*64, +64)
            __hip_atomic_store(
                (unsigned long long*)&mask[((size_t)t * BB + b) * 64] + (cg * 4 + w),
                bal, __ATOMIC_RELAXED, __HIP_MEMORY_SCOPE_AGENT);
            scnt += (uint32_t)__popcll(bal);
        }
        __syncthreads();   // drains all 4 waves' mask stores (vmcnt(0) before barrier)
        if (tid == 0)      // release: publish flag byte cg for (t,b)
            __hip_atomic_store(
                (uint8_t*)&flags[(size_t)(t * BB + b) * FLAG_STRIDE] + cg, (uint8_t)0xFF,
                __ATOMIC_RELEASE, __HIP_MEMORY_SCOPE_AGENT);
        __builtin_amdgcn_sched_barrier(0);   // keep prefetch BELOW the release store
        if (t + 1 < TT)    // prefetch next drive; latency hides under next poll+list
            dv = drive[((size_t)(t + 1) * BB + b) * RR + col];
    }

    if (lane == 0) s_red[w] = scnt;
    __syncthreads();
    if (tid == 0) {
        uint32_t s = s_red[0] + s_red[1] + s_red[2] + s_red[3];
        if (s) atomicAdd(&cnts[0], s);
    }
}

// ---------------- head: logits[t,b,:] = s @ w_head + b_head (sparse gather) ----------------
__global__ __launch_bounds__(128) void k_head(const uint32_t* __restrict__ mask,
                                              const float* __restrict__ w_head,
                                              const float* __restrict__ b_head,
                                              float* __restrict__ logits) {
    __shared__ __align__(16) int s_list[RR];   // byte offsets (row*512), 8 KB
    __shared__ int s_n;
    int tb = blockIdx.x;        // t*64 + b
    int tid = threadIdx.x;      // 0..127
    if (tid < 64) {             // wave 0: build ascending spike list (same as k_scan)
        uint32_t m = mask[tb * 64 + tid];
        int p = __popc(m);
        int off = p;
        #pragma unroll
        for (int d = 1; d < 64; d <<= 1) {
            int o = __shfl_up(off, d);
            if (tid >= d) off += o;
        }
        if (tid == 63) s_n = off;
        int e = off - p;
        int base = tid << 5;
        while (m) {
            int bit = __builtin_ctz(m);
            m &= m - 1;
            s_list[e++] = (base + bit) << 9;   // byte offset = row * DOUT * 4
        }
    }
    __syncthreads();
    const char* Wp = (const char*)(w_head + tid);
    float acc = b_head[tid];
    const int n = s_n;
    int i = 0;
    for (; i + 16 <= n; i += 16) {
        float v[16];
        #pragma unroll
        for (int u = 0; u < 16; u += 4) {
            int4 o = *(const int4*)&s_list[i + u];
            v[u + 0] = *(const float*)(Wp + o.x);
            v[u + 1] = *(const float*)(Wp + o.y);
            v[u + 2] = *(const float*)(Wp + o.z);
            v[u + 3] = *(const float*)(Wp + o.w);
        }
        __builtin_amdgcn_sched_barrier(0);
        #pragma unroll
        for (int j = 0; j < 16; ++j) acc += v[j];   // ascending order
    }
    for (; i < n; ++i) acc += *(const float*)(Wp + s_list[i]);
    logits[(size_t)tb * DOUT + tid] = acc;
}

__global__ __launch_bounds__(128) void k_readout(const float* __restrict__ logits,
                                                 float* __restrict__ readout) {
    int b = blockIdx.x, cidx = threadIdx.x;
    float s = 0.0f;
    for (int t = 0; t < TT; ++t)
        s += logits[(size_t)t * (BB * DOUT) + b * DOUT + cidx];
    readout[b * DOUT + cidx] = s * (1.0f / (float)TT);
}

__global__ void k_scalars(const uint32_t* __restrict__ cnts, float* __restrict__ out) {
    if (threadIdx.x == 0 && blockIdx.x == 0) {
        out[BB * DOUT + TT * BB * DOUT]     = (float)cnts[0] / (float)(TT * BB * RR);
        out[BB * DOUT + TT * BB * DOUT + 1] = (float)cnts[1] / (float)NTOT;
    }
}

extern "C" void kernel_launch(void* const* d_in, const int* in_sizes, int n_in,
                              void* d_out, int out_size, void* d_ws, size_t ws_size,
                              hipStream_t stream) {
    const float* x      = (const float*)d_in[0];
    const float* w_in   = (const float*)d_in[1];
    const float* b_in   = (const float*)d_in[2];
    float*       w_rec  = (float*)d_in[3];        // masked in place (restored each launch)
    const float* w_head = (const float*)d_in[4];
    const float* b_head = (const float*)d_in[5];
    float* out = (float*)d_out;

    float*    drive = (float*)d_ws;
    uint32_t* mask  = (uint32_t*)((char*)d_ws + 134217728u);
    unsigned long long* flags = (unsigned long long*)(mask + (TT * BB * 64));
    uint32_t* hist  = (uint32_t*)(flags + (size_t)TT * BB * FLAG_STRIDE);
    uint32_t* state = hist + 256;
    uint32_t* cnts  = state + 8;

    // zero flags + hist + state + cnts (contiguous; mask fully overwritten before read)
    k_init<<<256, 256, 0, stream>>>((uint32_t*)flags,
                                    TT * BB * FLAG_STRIDE * 2 + 256 + 8 + 2);

    for (int p = 0; p < 4; ++p) {
        k_hist<<<1024, 256, 0, stream>>>(w_rec, hist, state, p);
        k_select<<<1, 256, 0, stream>>>(hist, state, p);
    }
    k_maskcount<<<1024, 256, 0, stream>>>(w_rec, state, cnts);

    k_drive<<<dim3(128, 16), 256, 0, stream>>>(x, w_in, b_in, drive);

    k_scan<<<512, 256, 0, stream>>>(w_rec, drive, mask, flags, cnts);

    k_head<<<TT * BB, 128, 0, stream>>>(mask, w_head, b_head, out + BB * DOUT);
    k_readout<<<BB, 128, 0, stream>>>(out + BB * DOUT, out);
    k_scalars<<<1, 64, 0, stream>>>(cnts, out);
}